// Round 1
// baseline (178.840 us; speedup 1.0000x reference)
//
#include <hip/hip_runtime.h>

// Problem constants (match reference)
constexpr int BB  = 4096;          // B
constexpr int AA  = 64;            // A
constexpr int LLM = 64;            // L*M = 16*4 (inner x slot count)
constexpr int ED  = 10;            // E
constexpr int P1N = 32, P2N = 128, P3N = 256;
constexpr int PT  = P1N + P2N + P3N;   // 416
constexpr int WCE = 12;            // padded e-dim for float4 loads
constexpr int NB  = 4;             // batch rows per block

// ---------------------------------------------------------------------------
// Setup: wcT[p][a][12] = coeff[p] * w[e, k[p], q[p], a]  (e<10; 10,11 = 0)
// ---------------------------------------------------------------------------
__global__ void build_wc_kernel(
    const float* __restrict__ w1, const float* __restrict__ w2, const float* __restrict__ w3,
    const float* __restrict__ c1, const float* __restrict__ c2, const float* __restrict__ c3,
    const int* __restrict__ k1, const int* __restrict__ q1,
    const int* __restrict__ k2, const int* __restrict__ q2,
    const int* __restrict__ k3, const int* __restrict__ q3,
    float* __restrict__ wcT) {
  const int p = blockIdx.x;   // 0..415
  const int a = threadIdx.x;  // 0..63
  const float* w; float coeff; int k, q, K, Q;
  if (p < P1N)              { w = w1; coeff = c1[p];              k = k1[p];         q = q1[p];         K = 4;  Q = 2; }
  else if (p < P1N + P2N)   { int pp = p - P1N;       w = w2; coeff = c2[pp]; k = k2[pp]; q = q2[pp];   K = 16; Q = 4; }
  else                      { int pp = p - P1N - P2N; w = w3; coeff = c3[pp]; k = k3[pp]; q = q3[pp];   K = 32; Q = 6; }
  float* dst = wcT + ((size_t)p * AA + a) * WCE;
  #pragma unroll
  for (int e = 0; e < ED; ++e)
    dst[e] = coeff * w[(((size_t)e * K + k) * Q + q) * AA + a];
  dst[10] = 0.f;
  dst[11] = 0.f;
}

// ---------------------------------------------------------------------------
// Main contraction: one block = NB batch rows x 64 'a' channels.
// thread t: b_local = t>>6 (wave), a = t&63 (lane).
// ---------------------------------------------------------------------------
__global__ __launch_bounds__(256, 2)
void contract_kernel(const float* __restrict__ x, const float* __restrict__ y,
                     const float* __restrict__ wcT,
                     const int* __restrict__ i1, const int* __restrict__ l1,
                     const int* __restrict__ i2, const int* __restrict__ j2,
                     const int* __restrict__ l2, const int* __restrict__ m2,
                     const int* __restrict__ i3, const int* __restrict__ j3,
                     const int* __restrict__ f3, const int* __restrict__ l3,
                     const int* __restrict__ m3, const int* __restrict__ g3,
                     float* __restrict__ out) {
  // x tile: [b][a][65] padded rows -> reads xrow[xi] (lane=a, stride 65) are
  // 2 lanes/bank = conflict-free. ~66.6 KB.
  __shared__ float xs[NB][AA * 65];
  __shared__ int xiA[PT], xiB[PT], xiC[PT];

  const int t  = threadIdx.x;
  const int b0 = blockIdx.x * NB;

  // Stage combined x-indices (i*4+l) for all p once.
  for (int p = t; p < PT; p += 256) {
    int va, vb = 0, vc = 0;
    if (p < P1N) {
      va = i1[p] * 4 + l1[p];
    } else if (p < P1N + P2N) {
      int pp = p - P1N;
      va = i2[pp] * 4 + l2[pp];
      vb = j2[pp] * 4 + m2[pp];
    } else {
      int pp = p - P1N - P2N;
      va = i3[pp] * 4 + l3[pp];
      vb = j3[pp] * 4 + m3[pp];
      vc = f3[pp] * 4 + g3[pp];
    }
    xiA[p] = va; xiB[p] = vb; xiC[p] = vc;
  }

  // Stage x slices: 4096 floats per b, coalesced float4 reads.
  #pragma unroll
  for (int b = 0; b < NB; ++b) {
    const float4* src = (const float4*)(x + (size_t)(b0 + b) * (AA * LLM));
    for (int g4 = t; g4 < (AA * LLM) / 4; g4 += 256) {
      float4 v = src[g4];
      int g = g4 * 4;
      float* d = &xs[b][(g >> 6) * 65 + (g & 63)];
      d[0] = v.x; d[1] = v.y; d[2] = v.z; d[3] = v.w;
    }
  }
  __syncthreads();

  const int bl = t >> 6;
  const int a  = t & 63;
  const float* __restrict__ xrow = &xs[bl][a * 65];

  float yr[ED];
  {
    const float* yb = y + (size_t)(b0 + bl) * ED;
    #pragma unroll
    for (int e = 0; e < ED; ++e) yr[e] = yb[e];
  }

  const float4* __restrict__ wc4 = (const float4*)wcT;
  float acc = 0.f;

  // ---- path 1: single x factor ----
  #pragma unroll 4
  for (int p = 0; p < P1N; ++p) {
    const float4* wp = wc4 + ((size_t)p * AA + a) * 3;
    float4 u0 = wp[0], u1 = wp[1], u2 = wp[2];
    float g = u0.x * yr[0] + u0.y * yr[1] + u0.z * yr[2] + u0.w * yr[3]
            + u1.x * yr[4] + u1.y * yr[5] + u1.z * yr[6] + u1.w * yr[7]
            + u2.x * yr[8] + u2.y * yr[9];
    acc += g * xrow[xiA[p]];
  }

  // ---- path 2: two x factors ----
  #pragma unroll 4
  for (int p = P1N; p < P1N + P2N; ++p) {
    const float4* wp = wc4 + ((size_t)p * AA + a) * 3;
    float4 u0 = wp[0], u1 = wp[1], u2 = wp[2];
    float g = u0.x * yr[0] + u0.y * yr[1] + u0.z * yr[2] + u0.w * yr[3]
            + u1.x * yr[4] + u1.y * yr[5] + u1.z * yr[6] + u1.w * yr[7]
            + u2.x * yr[8] + u2.y * yr[9];
    acc += g * (xrow[xiA[p]] * xrow[xiB[p]]);
  }

  // ---- path 3: three x factors ----
  #pragma unroll 4
  for (int p = P1N + P2N; p < PT; ++p) {
    const float4* wp = wc4 + ((size_t)p * AA + a) * 3;
    float4 u0 = wp[0], u1 = wp[1], u2 = wp[2];
    float g = u0.x * yr[0] + u0.y * yr[1] + u0.z * yr[2] + u0.w * yr[3]
            + u1.x * yr[4] + u1.y * yr[5] + u1.z * yr[6] + u1.w * yr[7]
            + u2.x * yr[8] + u2.y * yr[9];
    acc += g * (xrow[xiA[p]] * xrow[xiB[p]]) * xrow[xiC[p]];
  }

  out[(size_t)(b0 + bl) * AA + a] = acc;
}

// ---------------------------------------------------------------------------
extern "C" void kernel_launch(void* const* d_in, const int* in_sizes, int n_in,
                              void* d_out, int out_size, void* d_ws, size_t ws_size,
                              hipStream_t stream) {
  const float* x  = (const float*)d_in[0];
  const float* y  = (const float*)d_in[1];
  const float* w1 = (const float*)d_in[2];
  const float* w2 = (const float*)d_in[3];
  const float* w3 = (const float*)d_in[4];
  const float* c1 = (const float*)d_in[5];
  const float* c2 = (const float*)d_in[6];
  const float* c3 = (const float*)d_in[7];
  const int* i1 = (const int*)d_in[8];
  const int* l1 = (const int*)d_in[9];
  const int* k1 = (const int*)d_in[10];
  const int* q1 = (const int*)d_in[11];
  const int* i2 = (const int*)d_in[12];
  const int* j2 = (const int*)d_in[13];
  const int* l2 = (const int*)d_in[14];
  const int* m2 = (const int*)d_in[15];
  const int* k2 = (const int*)d_in[16];
  const int* q2 = (const int*)d_in[17];
  const int* i3 = (const int*)d_in[18];
  const int* j3 = (const int*)d_in[19];
  const int* f3 = (const int*)d_in[20];
  const int* l3 = (const int*)d_in[21];
  const int* m3 = (const int*)d_in[22];
  const int* g3 = (const int*)d_in[23];
  const int* k3 = (const int*)d_in[24];
  const int* q3 = (const int*)d_in[25];

  float* wcT = (float*)d_ws;   // PT*64*12 floats = 1.25 MB

  build_wc_kernel<<<PT, AA, 0, stream>>>(w1, w2, w3, c1, c2, c3,
                                         k1, q1, k2, q2, k3, q3, wcT);
  contract_kernel<<<BB / NB, 256, 0, stream>>>(x, y, wcT,
                                               i1, l1, i2, j2, l2, m2,
                                               i3, j3, f3, l3, m3, g3,
                                               (float*)d_out);
}

// Round 2
// 139.101 us; speedup vs baseline: 1.2857x; 1.2857x over previous
//
#include <hip/hip_runtime.h>

// Problem constants (match reference)
constexpr int BB  = 4096;          // B
constexpr int AA  = 64;            // A
constexpr int ED  = 10;            // E
constexpr int P1N = 32, P2N = 128, P3N = 256;
constexpr int PT  = P1N + P2N + P3N;   // 416
constexpr int WCE = 12;            // record: 10 gate floats + packed idx + pad
constexpr int BCH = 256;           // batch rows per block

// ---------------------------------------------------------------------------
// Setup: cwA[a][p][12]:
//   [0..9]  = coeff[p] * w[e, k[p], q[p], a]
//   [10]    = bitcast(packed x-indices: xiA | xiB<<8 | xiC<<16)
//   [11]    = 0
// a-major so the main kernel's per-block slice (one a) is contiguous and
// all loads of it are wave-uniform -> scalar (s_load) loads.
// ---------------------------------------------------------------------------
__global__ void build_cw_kernel(
    const float* __restrict__ w1, const float* __restrict__ w2, const float* __restrict__ w3,
    const float* __restrict__ c1, const float* __restrict__ c2, const float* __restrict__ c3,
    const int* __restrict__ k1, const int* __restrict__ q1,
    const int* __restrict__ k2, const int* __restrict__ q2,
    const int* __restrict__ k3, const int* __restrict__ q3,
    const int* __restrict__ i1, const int* __restrict__ l1,
    const int* __restrict__ i2, const int* __restrict__ j2,
    const int* __restrict__ l2, const int* __restrict__ m2,
    const int* __restrict__ i3, const int* __restrict__ j3,
    const int* __restrict__ f3, const int* __restrict__ l3,
    const int* __restrict__ m3, const int* __restrict__ g3,
    float* __restrict__ cwA) {
  const int p = blockIdx.x;   // 0..415
  const int a = threadIdx.x;  // 0..63
  const float* w; float coeff; int k, q, K, Q;
  int xa = 0, xb = 0, xc = 0;
  if (p < P1N) {
    w = w1; coeff = c1[p]; k = k1[p]; q = q1[p]; K = 4;  Q = 2;
    xa = i1[p] * 4 + l1[p];
  } else if (p < P1N + P2N) {
    int pp = p - P1N;
    w = w2; coeff = c2[pp]; k = k2[pp]; q = q2[pp]; K = 16; Q = 4;
    xa = i2[pp] * 4 + l2[pp];
    xb = j2[pp] * 4 + m2[pp];
  } else {
    int pp = p - P1N - P2N;
    w = w3; coeff = c3[pp]; k = k3[pp]; q = q3[pp]; K = 32; Q = 6;
    xa = i3[pp] * 4 + l3[pp];
    xb = j3[pp] * 4 + m3[pp];
    xc = f3[pp] * 4 + g3[pp];
  }
  float* dst = cwA + ((size_t)a * PT + p) * WCE;
  #pragma unroll
  for (int e = 0; e < ED; ++e)
    dst[e] = coeff * w[(((size_t)e * K + k) * Q + q) * AA + a];
  dst[10] = __int_as_float(xa | (xb << 8) | (xc << 16));
  dst[11] = 0.f;
}

// ---------------------------------------------------------------------------
// Main: block = 256 b's x ONE a. lane -> b, so all cw/idx accesses are
// wave-uniform (scalar loads). x tile staged in LDS [256][65] (pad -> the
// runtime-indexed row reads, stride 65 across lanes, are conflict-free).
// ---------------------------------------------------------------------------
__global__ __launch_bounds__(256, 2)
void contract_kernel(const float* __restrict__ x, const float* __restrict__ y,
                     const float* __restrict__ cwA,
                     float* __restrict__ out) {
  __shared__ float xls[BCH][65];

  const int t  = threadIdx.x;
  const int a  = blockIdx.x >> 4;          // 0..63
  const int b0 = (blockIdx.x & 15) * BCH;  // 0..3840

  // Stage x[b0..b0+255][a][0..63]: thread t reads float4 at (b=t>>4, s4=t&15).
  // 16 lanes x 16B = 256B contiguous per b-row, coalesced.
  for (int g4 = t; g4 < BCH * 16; g4 += 256) {
    const int b = g4 >> 4, s4 = g4 & 15;
    const float4 v = *(const float4*)(x + (size_t)(b0 + b) * 4096 + a * 64 + s4 * 4);
    float* d = &xls[b][s4 * 4];
    d[0] = v.x; d[1] = v.y; d[2] = v.z; d[3] = v.w;
  }

  float yr[ED];
  {
    const float* yb = y + (size_t)(b0 + t) * ED;
    #pragma unroll
    for (int e = 0; e < ED; ++e) yr[e] = yb[e];
  }

  __syncthreads();

  const float* __restrict__ row = &xls[t][0];
  const float4* __restrict__ cw4 = (const float4*)cwA + (size_t)a * PT * 3;

  float acc = 0.f;

  // ---- path 1: single x factor ----
  #pragma unroll 8
  for (int p = 0; p < P1N; ++p) {
    const float4 u0 = cw4[p * 3 + 0];
    const float4 u1 = cw4[p * 3 + 1];
    const float4 u2 = cw4[p * 3 + 2];
    float g = u0.x * yr[0] + u0.y * yr[1] + u0.z * yr[2] + u0.w * yr[3]
            + u1.x * yr[4] + u1.y * yr[5] + u1.z * yr[6] + u1.w * yr[7]
            + u2.x * yr[8] + u2.y * yr[9];
    const int pk = __float_as_int(u2.z);
    acc += g * row[pk & 63];
  }

  // ---- path 2: two x factors ----
  #pragma unroll 4
  for (int p = P1N; p < P1N + P2N; ++p) {
    const float4 u0 = cw4[p * 3 + 0];
    const float4 u1 = cw4[p * 3 + 1];
    const float4 u2 = cw4[p * 3 + 2];
    float g = u0.x * yr[0] + u0.y * yr[1] + u0.z * yr[2] + u0.w * yr[3]
            + u1.x * yr[4] + u1.y * yr[5] + u1.z * yr[6] + u1.w * yr[7]
            + u2.x * yr[8] + u2.y * yr[9];
    const int pk = __float_as_int(u2.z);
    acc += g * (row[pk & 63] * row[(pk >> 8) & 63]);
  }

  // ---- path 3: three x factors ----
  #pragma unroll 4
  for (int p = P1N + P2N; p < PT; ++p) {
    const float4 u0 = cw4[p * 3 + 0];
    const float4 u1 = cw4[p * 3 + 1];
    const float4 u2 = cw4[p * 3 + 2];
    float g = u0.x * yr[0] + u0.y * yr[1] + u0.z * yr[2] + u0.w * yr[3]
            + u1.x * yr[4] + u1.y * yr[5] + u1.z * yr[6] + u1.w * yr[7]
            + u2.x * yr[8] + u2.y * yr[9];
    const int pk = __float_as_int(u2.z);
    acc += g * (row[pk & 63] * row[(pk >> 8) & 63]) * row[(pk >> 16) & 63];
  }

  out[(size_t)(b0 + t) * AA + a] = acc;
}

// ---------------------------------------------------------------------------
extern "C" void kernel_launch(void* const* d_in, const int* in_sizes, int n_in,
                              void* d_out, int out_size, void* d_ws, size_t ws_size,
                              hipStream_t stream) {
  const float* x  = (const float*)d_in[0];
  const float* y  = (const float*)d_in[1];
  const float* w1 = (const float*)d_in[2];
  const float* w2 = (const float*)d_in[3];
  const float* w3 = (const float*)d_in[4];
  const float* c1 = (const float*)d_in[5];
  const float* c2 = (const float*)d_in[6];
  const float* c3 = (const float*)d_in[7];
  const int* i1 = (const int*)d_in[8];
  const int* l1 = (const int*)d_in[9];
  const int* k1 = (const int*)d_in[10];
  const int* q1 = (const int*)d_in[11];
  const int* i2 = (const int*)d_in[12];
  const int* j2 = (const int*)d_in[13];
  const int* l2 = (const int*)d_in[14];
  const int* m2 = (const int*)d_in[15];
  const int* k2 = (const int*)d_in[16];
  const int* q2 = (const int*)d_in[17];
  const int* i3 = (const int*)d_in[18];
  const int* j3 = (const int*)d_in[19];
  const int* f3 = (const int*)d_in[20];
  const int* l3 = (const int*)d_in[21];
  const int* m3 = (const int*)d_in[22];
  const int* g3 = (const int*)d_in[23];
  const int* k3 = (const int*)d_in[24];
  const int* q3 = (const int*)d_in[25];

  float* cwA = (float*)d_ws;   // AA*PT*12 floats = 1.28 MB

  build_cw_kernel<<<PT, AA, 0, stream>>>(w1, w2, w3, c1, c2, c3,
                                         k1, q1, k2, q2, k3, q3,
                                         i1, l1, i2, j2, l2, m2,
                                         i3, j3, f3, l3, m3, g3, cwA);
  contract_kernel<<<AA * (BB / BCH), 256, 0, stream>>>(x, y, cwA, (float*)d_out);
}

// Round 3
// 64.165 us; speedup vs baseline: 2.7872x; 2.1679x over previous
//
#include <hip/hip_runtime.h>

// Problem constants (match reference)
constexpr int BB  = 4096;          // B
constexpr int AA  = 64;            // A
constexpr int ED  = 10;            // E
constexpr int P1N = 32, P2N = 128, P3N = 256;
constexpr int PT  = P1N + P2N + P3N;   // 416
constexpr int WCE = 12;            // record: 10 gate floats + packed idx + pad
constexpr int BCH = 128;           // batch rows per block
constexpr int PSPLIT = 208;        // p-range split between wave-pairs

// ---------------------------------------------------------------------------
// Setup: cwA[a][p][12]:
//   [0..9]  = coeff[p] * w[e, k[p], q[p], a]
//   [10]    = bitcast(packed x-indices: ia | ib<<8 | ic<<16), unused idx = 64
//             (slot 64 of the LDS x row holds constant 1.0f)
//   [11]    = 0
// ---------------------------------------------------------------------------
__global__ void build_cw_kernel(
    const float* __restrict__ w1, const float* __restrict__ w2, const float* __restrict__ w3,
    const float* __restrict__ c1, const float* __restrict__ c2, const float* __restrict__ c3,
    const int* __restrict__ k1, const int* __restrict__ q1,
    const int* __restrict__ k2, const int* __restrict__ q2,
    const int* __restrict__ k3, const int* __restrict__ q3,
    const int* __restrict__ i1, const int* __restrict__ l1,
    const int* __restrict__ i2, const int* __restrict__ j2,
    const int* __restrict__ l2, const int* __restrict__ m2,
    const int* __restrict__ i3, const int* __restrict__ j3,
    const int* __restrict__ f3, const int* __restrict__ l3,
    const int* __restrict__ m3, const int* __restrict__ g3,
    float* __restrict__ cwA) {
  const int p = blockIdx.x;   // 0..415
  const int a = threadIdx.x;  // 0..63
  const float* w; float coeff; int k, q, K, Q;
  int xa, xb = 64, xc = 64;   // 64 -> constant-1.0 slot
  if (p < P1N) {
    w = w1; coeff = c1[p]; k = k1[p]; q = q1[p]; K = 4;  Q = 2;
    xa = i1[p] * 4 + l1[p];
  } else if (p < P1N + P2N) {
    int pp = p - P1N;
    w = w2; coeff = c2[pp]; k = k2[pp]; q = q2[pp]; K = 16; Q = 4;
    xa = i2[pp] * 4 + l2[pp];
    xb = j2[pp] * 4 + m2[pp];
  } else {
    int pp = p - P1N - P2N;
    w = w3; coeff = c3[pp]; k = k3[pp]; q = q3[pp]; K = 32; Q = 6;
    xa = i3[pp] * 4 + l3[pp];
    xb = j3[pp] * 4 + m3[pp];
    xc = f3[pp] * 4 + g3[pp];
  }
  float* dst = cwA + ((size_t)a * PT + p) * WCE;
  #pragma unroll
  for (int e = 0; e < ED; ++e)
    dst[e] = coeff * w[(((size_t)e * K + k) * Q + q) * AA + a];
  dst[10] = __int_as_float(xa | (xb << 8) | (xc << 16));
  dst[11] = 0.f;
}

// ---------------------------------------------------------------------------
// Main: block = 128 b's x ONE a x 2 p-halves.
// thread t: bl = t&127, ph = t>>7 (wave-uniform -> record loads stay scalar).
// x tile [128][65] padded (runtime-indexed reads are 2 lanes/bank = free);
// slot [64] = 1.0f so every record is row[ia]*row[ib]*row[ic].
// h-form accumulation: h[e] += cw[p][e]*xprod  (10 independent v_fmac,
// scalar operand) -> ds_read result feeds independent FMAs, no gate chain.
// ---------------------------------------------------------------------------
__global__ __launch_bounds__(256, 4)
void contract_kernel(const float* __restrict__ x, const float* __restrict__ y,
                     const float* __restrict__ cwA,
                     float* __restrict__ out) {
  __shared__ float xls[BCH][65];
  __shared__ float part[BCH];

  const int t  = threadIdx.x;
  const int a  = blockIdx.x & 63;           // 64 consecutive blocks share b-range
  const int b0 = (blockIdx.x >> 6) * BCH;

  // Stage x[b0..b0+127][a][0..63]: 2048 float4, coalesced 256B per b-row.
  for (int g4 = t; g4 < BCH * 16; g4 += 256) {
    const int b = g4 >> 4, s4 = g4 & 15;
    const float4 v = *(const float4*)(x + (size_t)(b0 + b) * 4096 + a * 64 + s4 * 4);
    float* d = &xls[b][s4 * 4];
    d[0] = v.x; d[1] = v.y; d[2] = v.z; d[3] = v.w;
  }
  if (t < BCH) xls[t][64] = 1.0f;
  __syncthreads();

  const int bl = t & (BCH - 1);
  const int ph = t >> 7;
  const float* __restrict__ row = &xls[bl][0];
  const float4* __restrict__ cw4 = (const float4*)cwA + (size_t)a * PT * 3;

  float h0 = 0.f, h1 = 0.f, h2 = 0.f, h3 = 0.f, h4 = 0.f;
  float h5 = 0.f, h6 = 0.f, h7 = 0.f, h8 = 0.f, h9 = 0.f;

  auto body = [&](int p) {
    const float4 u0 = cw4[p * 3 + 0];
    const float4 u1 = cw4[p * 3 + 1];
    const float4 u2 = cw4[p * 3 + 2];
    const int pk = __float_as_int(u2.z);
    const float xp = row[pk & 255] * row[(pk >> 8) & 255] * row[(pk >> 16) & 255];
    h0 += u0.x * xp; h1 += u0.y * xp; h2 += u0.z * xp; h3 += u0.w * xp;
    h4 += u1.x * xp; h5 += u1.y * xp; h6 += u1.z * xp; h7 += u1.w * xp;
    h8 += u2.x * xp; h9 += u2.y * xp;
  };

  if (ph == 0) {
    #pragma unroll 4
    for (int p = 0; p < PSPLIT; ++p) body(p);
  } else {
    #pragma unroll 4
    for (int p = PSPLIT; p < PT; ++p) body(p);
  }

  // y-dot once, outside the loop.
  const float* yb = y + (size_t)(b0 + bl) * ED;
  const float val = yb[0] * h0 + yb[1] * h1 + yb[2] * h2 + yb[3] * h3
                  + yb[4] * h4 + yb[5] * h5 + yb[6] * h6 + yb[7] * h7
                  + yb[8] * h8 + yb[9] * h9;

  if (ph == 1) part[bl] = val;
  __syncthreads();
  if (ph == 0) out[(size_t)(b0 + bl) * AA + a] = val + part[bl];
}

// ---------------------------------------------------------------------------
extern "C" void kernel_launch(void* const* d_in, const int* in_sizes, int n_in,
                              void* d_out, int out_size, void* d_ws, size_t ws_size,
                              hipStream_t stream) {
  const float* x  = (const float*)d_in[0];
  const float* y  = (const float*)d_in[1];
  const float* w1 = (const float*)d_in[2];
  const float* w2 = (const float*)d_in[3];
  const float* w3 = (const float*)d_in[4];
  const float* c1 = (const float*)d_in[5];
  const float* c2 = (const float*)d_in[6];
  const float* c3 = (const float*)d_in[7];
  const int* i1 = (const int*)d_in[8];
  const int* l1 = (const int*)d_in[9];
  const int* k1 = (const int*)d_in[10];
  const int* q1 = (const int*)d_in[11];
  const int* i2 = (const int*)d_in[12];
  const int* j2 = (const int*)d_in[13];
  const int* l2 = (const int*)d_in[14];
  const int* m2 = (const int*)d_in[15];
  const int* k2 = (const int*)d_in[16];
  const int* q2 = (const int*)d_in[17];
  const int* i3 = (const int*)d_in[18];
  const int* j3 = (const int*)d_in[19];
  const int* f3 = (const int*)d_in[20];
  const int* l3 = (const int*)d_in[21];
  const int* m3 = (const int*)d_in[22];
  const int* g3 = (const int*)d_in[23];
  const int* k3 = (const int*)d_in[24];
  const int* q3 = (const int*)d_in[25];

  float* cwA = (float*)d_ws;   // AA*PT*12 floats = 1.28 MB

  build_cw_kernel<<<PT, AA, 0, stream>>>(w1, w2, w3, c1, c2, c3,
                                         k1, q1, k2, q2, k3, q3,
                                         i1, l1, i2, j2, l2, m2,
                                         i3, j3, f3, l3, m3, g3, cwA);
  contract_kernel<<<AA * (BB / BCH), 256, 0, stream>>>(x, y, cwA, (float*)d_out);
}

// Round 4
// 57.968 us; speedup vs baseline: 3.0852x; 1.1069x over previous
//
#include <hip/hip_runtime.h>
#include <hip/hip_bf16.h>

typedef short  bf16x8 __attribute__((ext_vector_type(8)));
typedef float  f32x4  __attribute__((ext_vector_type(4)));

constexpr int BB  = 4096;
constexpr int AA  = 64;
constexpr int ED  = 10;
constexpr int P1N = 32, P2N = 128, P3N = 256;
constexpr int PT  = 416;          // = 13 * 32 exactly
constexpr int NKS = 13;           // K-steps of 32
constexpr int BCH = 64;           // b rows per block

// ws layout: [0,1664): idxs[416] packed slot-triples
//            [4096, 4096+851968): cwb bf16 B-frags [a][ks][lane][8]

__device__ inline short f2bf(float f) {
  __hip_bfloat16 h = __float2bfloat16(f);
  short s;
  __builtin_memcpy(&s, &h, 2);
  return s;
}

// ---------------------------------------------------------------------------
// idxs[p] = sa | sb<<10 | sc<<20   (slot indices 0..64; 64 = constant-1 slot)
// ---------------------------------------------------------------------------
__global__ void build_idx_kernel(
    const int* __restrict__ i1, const int* __restrict__ l1,
    const int* __restrict__ i2, const int* __restrict__ j2,
    const int* __restrict__ l2, const int* __restrict__ m2,
    const int* __restrict__ i3, const int* __restrict__ j3,
    const int* __restrict__ f3, const int* __restrict__ l3,
    const int* __restrict__ m3, const int* __restrict__ g3,
    unsigned* __restrict__ idxs) {
  const int p = threadIdx.x;
  if (p >= PT) return;
  unsigned sa, sb = 64, sc = 64;
  if (p < P1N) {
    sa = i1[p] * 4 + l1[p];
  } else if (p < P1N + P2N) {
    int pp = p - P1N;
    sa = i2[pp] * 4 + l2[pp];
    sb = j2[pp] * 4 + m2[pp];
  } else {
    int pp = p - P1N - P2N;
    sa = i3[pp] * 4 + l3[pp];
    sb = j3[pp] * 4 + m3[pp];
    sc = f3[pp] * 4 + g3[pp];
  }
  idxs[p] = sa | (sb << 10) | (sc << 20);
}

// ---------------------------------------------------------------------------
// B-frag table: cwb[a][ks][lane][j] = bf16( coeff[p] * w[e, k[p], q[p], a] )
// with p = ks*32 + (lane>>4)*8 + j, e = lane&15 (0 for e>=10).
// Same (lane,j)->p map as the A-frag generation in the main kernel.
// ---------------------------------------------------------------------------
__global__ void build_cwb_kernel(
    const float* __restrict__ w1, const float* __restrict__ w2, const float* __restrict__ w3,
    const float* __restrict__ c1, const float* __restrict__ c2, const float* __restrict__ c3,
    const int* __restrict__ k1, const int* __restrict__ q1,
    const int* __restrict__ k2, const int* __restrict__ q2,
    const int* __restrict__ k3, const int* __restrict__ q3,
    short* __restrict__ cwb) {
  const int a  = blockIdx.x & 63;
  const int ks = blockIdx.x >> 6;   // 0..12
  const int l  = threadIdx.x;       // 0..63
  const int grp = l >> 4, e = l & 15;
  short* dst = cwb + (((size_t)a * NKS + ks) * 64 + l) * 8;
  #pragma unroll
  for (int j = 0; j < 8; ++j) {
    const int p = ks * 32 + grp * 8 + j;
    float v = 0.f;
    if (e < ED) {
      const float* w; float coeff; int k, q, K, Q;
      if (p < P1N)            { w = w1; coeff = c1[p]; k = k1[p]; q = q1[p]; K = 4;  Q = 2; }
      else if (p < P1N + P2N) { int pp = p - P1N;       w = w2; coeff = c2[pp]; k = k2[pp]; q = q2[pp]; K = 16; Q = 4; }
      else                    { int pp = p - P1N - P2N; w = w3; coeff = c3[pp]; k = k3[pp]; q = q3[pp]; K = 32; Q = 6; }
      v = coeff * w[(((size_t)e * K + k) * Q + q) * AA + a];
    }
    dst[j] = f2bf(v);
  }
}

// ---------------------------------------------------------------------------
// Main: block = one a x 64 b's, 4 waves = 4 M-tiles of 16 rows.
// Per K-step: each lane builds its A-frag (8 xp products, row = lane&15),
// loads its B-frag (16B coalesced), one 16x16x32 bf16 MFMA, f32 accum.
// Epilogue: D[row][e] * y[b][e], 16-lane shfl-xor reduce over e, store.
// ---------------------------------------------------------------------------
__global__ __launch_bounds__(256, 6)
void contract_kernel(const float* __restrict__ x, const float* __restrict__ y,
                     const unsigned* __restrict__ idxs,
                     const bf16x8* __restrict__ cwb,
                     float* __restrict__ out) {
  __shared__ float xls[BCH][65];   // slot 64 = 1.0f
  __shared__ float yls[BCH][17];   // e padded to 16 with zeros

  const int t  = threadIdx.x;
  const int a  = blockIdx.x & 63;
  const int b0 = (blockIdx.x >> 6) * BCH;

  // Stage x[b0..b0+63][a][0..63]: 1024 float4, coalesced 256B per b-row.
  for (int g4 = t; g4 < BCH * 16; g4 += 256) {
    const int b = g4 >> 4, s4 = g4 & 15;
    const float4 v = *(const float4*)(x + (size_t)(b0 + b) * 4096 + a * 64 + s4 * 4);
    float* d = &xls[b][s4 * 4];
    d[0] = v.x; d[1] = v.y; d[2] = v.z; d[3] = v.w;
  }
  if (t < BCH) {
    xls[t][64] = 1.0f;
    const float* yb = y + (size_t)(b0 + t) * ED;
    #pragma unroll
    for (int e = 0; e < ED; ++e) yls[t][e] = yb[e];
    #pragma unroll
    for (int e = ED; e < 16; ++e) yls[t][e] = 0.f;
  }
  __syncthreads();

  const int wv = t >> 6, l = t & 63, grp = l >> 4, er = l & 15;
  const float* __restrict__ xrow = &xls[wv * 16 + er][0];   // A-row = lane&15
  const bf16x8* __restrict__ cwp = cwb + ((size_t)a * NKS) * 64 + l;
  const uint4*  __restrict__ ip  = (const uint4*)idxs + grp * 2;

  f32x4 acc = {0.f, 0.f, 0.f, 0.f};

  #pragma unroll 2
  for (int ks = 0; ks < NKS; ++ks) {
    const uint4 iA = ip[ks * 8 + 0];
    const uint4 iB = ip[ks * 8 + 1];
    const bf16x8 bfrag = cwp[ks * 64];

    auto XP = [&](unsigned pk) -> float {
      const float f0 = xrow[pk & 1023u];
      const float f1 = xrow[(pk >> 10) & 1023u];
      const float f2 = xrow[pk >> 20];
      return f0 * f1 * f2;
    };

    bf16x8 afrag;
    afrag[0] = f2bf(XP(iA.x));
    afrag[1] = f2bf(XP(iA.y));
    afrag[2] = f2bf(XP(iA.z));
    afrag[3] = f2bf(XP(iA.w));
    afrag[4] = f2bf(XP(iB.x));
    afrag[5] = f2bf(XP(iB.y));
    afrag[6] = f2bf(XP(iB.z));
    afrag[7] = f2bf(XP(iB.w));

    acc = __builtin_amdgcn_mfma_f32_16x16x32_bf16(afrag, bfrag, acc, 0, 0, 0);
  }

  // Epilogue: D[row = grp*4+v][col = er], rows are b-local within the M-tile.
  float s0 = acc[0] * yls[wv * 16 + grp * 4 + 0][er];
  float s1 = acc[1] * yls[wv * 16 + grp * 4 + 1][er];
  float s2 = acc[2] * yls[wv * 16 + grp * 4 + 2][er];
  float s3 = acc[3] * yls[wv * 16 + grp * 4 + 3][er];
  #pragma unroll
  for (int m = 1; m < 16; m <<= 1) {
    s0 += __shfl_xor(s0, m);
    s1 += __shfl_xor(s1, m);
    s2 += __shfl_xor(s2, m);
    s3 += __shfl_xor(s3, m);
  }
  if (er < 4) {
    const float sv = er == 0 ? s0 : er == 1 ? s1 : er == 2 ? s2 : s3;
    out[(size_t)(b0 + wv * 16 + grp * 4 + er) * AA + a] = sv;
  }
}

// ---------------------------------------------------------------------------
extern "C" void kernel_launch(void* const* d_in, const int* in_sizes, int n_in,
                              void* d_out, int out_size, void* d_ws, size_t ws_size,
                              hipStream_t stream) {
  const float* x  = (const float*)d_in[0];
  const float* y  = (const float*)d_in[1];
  const float* w1 = (const float*)d_in[2];
  const float* w2 = (const float*)d_in[3];
  const float* w3 = (const float*)d_in[4];
  const float* c1 = (const float*)d_in[5];
  const float* c2 = (const float*)d_in[6];
  const float* c3 = (const float*)d_in[7];
  const int* i1 = (const int*)d_in[8];
  const int* l1 = (const int*)d_in[9];
  const int* k1 = (const int*)d_in[10];
  const int* q1 = (const int*)d_in[11];
  const int* i2 = (const int*)d_in[12];
  const int* j2 = (const int*)d_in[13];
  const int* l2 = (const int*)d_in[14];
  const int* m2 = (const int*)d_in[15];
  const int* k2 = (const int*)d_in[16];
  const int* q2 = (const int*)d_in[17];
  const int* i3 = (const int*)d_in[18];
  const int* j3 = (const int*)d_in[19];
  const int* f3 = (const int*)d_in[20];
  const int* l3 = (const int*)d_in[21];
  const int* m3 = (const int*)d_in[22];
  const int* g3 = (const int*)d_in[23];
  const int* k3 = (const int*)d_in[24];
  const int* q3 = (const int*)d_in[25];

  unsigned* idxs = (unsigned*)d_ws;                    // 416*4 B
  short*    cwb  = (short*)((char*)d_ws + 4096);       // 64*13*64*8*2 B = 832 KB

  build_idx_kernel<<<1, 448, 0, stream>>>(i1, l1, i2, j2, l2, m2,
                                          i3, j3, f3, l3, m3, g3, idxs);
  build_cwb_kernel<<<AA * NKS, 64, 0, stream>>>(w1, w2, w3, c1, c2, c3,
                                                k1, q1, k2, q2, k3, q3, cwb);
  contract_kernel<<<AA * (BB / BCH), 256, 0, stream>>>(
      x, y, idxs, (const bf16x8*)cwb, (float*)d_out);
}

// Round 5
// 50.394 us; speedup vs baseline: 3.5488x; 1.1503x over previous
//
#include <hip/hip_runtime.h>
#include <hip/hip_bf16.h>

typedef short  bf16x8 __attribute__((ext_vector_type(8)));
typedef float  f32x4  __attribute__((ext_vector_type(4)));
typedef float  f32x2  __attribute__((ext_vector_type(2)));

constexpr int BB  = 4096;
constexpr int AA  = 64;
constexpr int ED  = 10;
constexpr int P1N = 32, P2N = 128, P3N = 256;
constexpr int PT  = 416;          // = 13 * 32
constexpr int NKS = 13;           // K-steps of 32
constexpr int BCH = 64;           // b rows per block

__device__ inline short f2bf(float f) {
  __hip_bfloat16 h = __float2bfloat16(f);
  short s;
  __builtin_memcpy(&s, &h, 2);
  return s;
}

// ---------------------------------------------------------------------------
// idxs[p] = sa | sb<<10 | sc<<20   (slot 0..64; 64 = constant-1 slot)
// ---------------------------------------------------------------------------
__global__ void build_idx_kernel(
    const int* __restrict__ i1, const int* __restrict__ l1,
    const int* __restrict__ i2, const int* __restrict__ j2,
    const int* __restrict__ l2, const int* __restrict__ m2,
    const int* __restrict__ i3, const int* __restrict__ j3,
    const int* __restrict__ f3, const int* __restrict__ l3,
    const int* __restrict__ m3, const int* __restrict__ g3,
    unsigned* __restrict__ idxs) {
  const int p = threadIdx.x;
  if (p >= PT) return;
  unsigned sa, sb = 64, sc = 64;
  if (p < P1N) {
    sa = i1[p] * 4 + l1[p];
  } else if (p < P1N + P2N) {
    int pp = p - P1N;
    sa = i2[pp] * 4 + l2[pp];
    sb = j2[pp] * 4 + m2[pp];
  } else {
    int pp = p - P1N - P2N;
    sa = i3[pp] * 4 + l3[pp];
    sb = j3[pp] * 4 + m3[pp];
    sc = f3[pp] * 4 + g3[pp];
  }
  idxs[p] = sa | (sb << 10) | (sc << 20);
}

// ---------------------------------------------------------------------------
// B-frag table: cwb[a][ks][lane][j] = bf16( coeff[p] * w[e,k[p],q[p],a] )
// p = ks*32 + (lane>>4)*8 + j, e = lane&15 (0 for e>=10).
// Same (lane,j)->p map as A-frag generation in the main kernel.
// ---------------------------------------------------------------------------
__global__ void build_cwb_kernel(
    const float* __restrict__ w1, const float* __restrict__ w2, const float* __restrict__ w3,
    const float* __restrict__ c1, const float* __restrict__ c2, const float* __restrict__ c3,
    const int* __restrict__ k1, const int* __restrict__ q1,
    const int* __restrict__ k2, const int* __restrict__ q2,
    const int* __restrict__ k3, const int* __restrict__ q3,
    short* __restrict__ cwb) {
  const int a  = blockIdx.x & 63;
  const int ks = blockIdx.x >> 6;   // 0..12
  const int l  = threadIdx.x;       // 0..63
  const int grp = l >> 4, e = l & 15;
  short* dst = cwb + (((size_t)a * NKS + ks) * 64 + l) * 8;
  #pragma unroll
  for (int j = 0; j < 8; ++j) {
    const int p = ks * 32 + grp * 8 + j;
    float v = 0.f;
    if (e < ED) {
      const float* w; float coeff; int k, q, K, Q;
      if (p < P1N)            { w = w1; coeff = c1[p]; k = k1[p]; q = q1[p]; K = 4;  Q = 2; }
      else if (p < P1N + P2N) { int pp = p - P1N;       w = w2; coeff = c2[pp]; k = k2[pp]; q = q2[pp]; K = 16; Q = 4; }
      else                    { int pp = p - P1N - P2N; w = w3; coeff = c3[pp]; k = k3[pp]; q = q3[pp]; K = 32; Q = 6; }
      v = coeff * w[(((size_t)e * K + k) * Q + q) * AA + a];
    }
    dst[j] = f2bf(v);
  }
}

// ---------------------------------------------------------------------------
// K-step body, specialized by number of x factors NF (1/2/3).
// One ds_read_b64 serves both a-channels (f32x2).
// ---------------------------------------------------------------------------
template <int NF>
__device__ __forceinline__ void kstep(const f32x2* __restrict__ row,
                                      const uint4* __restrict__ ip, int ks,
                                      const bf16x8* __restrict__ cwpA,
                                      const bf16x8* __restrict__ cwpB,
                                      f32x4& accA, f32x4& accB) {
  const uint4 iA = ip[ks * 8 + 0];
  const uint4 iB = ip[ks * 8 + 1];
  const bf16x8 bfA = cwpA[ks * 64];
  const bf16x8 bfB = cwpB[ks * 64];
  unsigned pks[8] = {iA.x, iA.y, iA.z, iA.w, iB.x, iB.y, iB.z, iB.w};
  f32x2 xp[8];
  #pragma unroll
  for (int j = 0; j < 8; ++j) {
    const unsigned pk = pks[j];
    f32x2 v = row[pk & 1023u];
    if (NF >= 2) v = v * row[(pk >> 10) & 1023u];
    if (NF >= 3) v = v * row[pk >> 20];
    xp[j] = v;
  }
  bf16x8 afA, afB;
  #pragma unroll
  for (int j = 0; j < 8; ++j) {
    afA[j] = f2bf(xp[j].x);
    afB[j] = f2bf(xp[j].y);
  }
  accA = __builtin_amdgcn_mfma_f32_16x16x32_bf16(afA, bfA, accA, 0, 0, 0);
  accB = __builtin_amdgcn_mfma_f32_16x16x32_bf16(afB, bfB, accB, 0, 0, 0);
}

// ---------------------------------------------------------------------------
// Main: block = a-pair (a0,a0+1) x 64 b's, 4 waves = 4 M-tiles of 16 rows.
// x tile as f32x2 (both a's) -> each runtime-indexed ds_read_b64 feeds 2 xp.
// K-loop split by path arity (boundaries 32/160 align with 32-wide K-steps).
// ---------------------------------------------------------------------------
__global__ __launch_bounds__(256, 4)
void contract_kernel(const float* __restrict__ x, const float* __restrict__ y,
                     const unsigned* __restrict__ idxs,
                     const bf16x8* __restrict__ cwb,
                     float* __restrict__ out) {
  __shared__ f32x2 xls[BCH][65];   // slot 64 = {1,1}
  __shared__ float yls[BCH][17];   // e padded to 16 with zeros

  const int t  = threadIdx.x;
  const int a0 = (blockIdx.x & 31) * 2;
  const int b0 = (blockIdx.x >> 5) * BCH;

  // Stage x[b][a0..a0+1][0..63]: 512B contiguous per b (two 64-float rows).
  for (int g = t; g < BCH * 32; g += 256) {
    const int b = g >> 5, c4 = g & 31;
    const float4 v = *(const float4*)(x + (size_t)(b0 + b) * 4096 + a0 * 64 + c4 * 4);
    const int comp = c4 >> 4;          // 0 -> a0 (.x), 1 -> a1 (.y)
    float* d = (float*)&xls[b][(c4 & 15) * 4] + comp;
    d[0] = v.x; d[2] = v.y; d[4] = v.z; d[6] = v.w;
  }
  if (t < BCH) {
    xls[t][64] = f32x2{1.0f, 1.0f};
    const float* yb = y + (size_t)(b0 + t) * ED;
    #pragma unroll
    for (int e = 0; e < ED; ++e) yls[t][e] = yb[e];
    #pragma unroll
    for (int e = ED; e < 16; ++e) yls[t][e] = 0.f;
  }
  __syncthreads();

  const int wv = t >> 6, l = t & 63, grp = l >> 4, er = l & 15;
  const f32x2* __restrict__ row = &xls[wv * 16 + er][0];   // A-row = lane&15
  const bf16x8* __restrict__ cwpA = cwb + ((size_t)a0 * NKS) * 64 + l;
  const bf16x8* __restrict__ cwpB = cwb + ((size_t)(a0 + 1) * NKS) * 64 + l;
  const uint4*  __restrict__ ip  = (const uint4*)idxs + grp * 2;

  f32x4 accA = {0.f, 0.f, 0.f, 0.f};
  f32x4 accB = {0.f, 0.f, 0.f, 0.f};

  kstep<1>(row, ip, 0, cwpA, cwpB, accA, accB);           // path 1: p 0..31
  #pragma unroll 2
  for (int ks = 1; ks < 5; ++ks)
    kstep<2>(row, ip, ks, cwpA, cwpB, accA, accB);        // path 2: p 32..159
  #pragma unroll 2
  for (int ks = 5; ks < NKS; ++ks)
    kstep<3>(row, ip, ks, cwpA, cwpB, accA, accB);        // path 3: p 160..415

  // Epilogue: D[row = grp*4+v][col = er], y-weight, 16-lane reduce over e.
  #pragma unroll
  for (int half = 0; half < 2; ++half) {
    const f32x4 acc = half ? accB : accA;
    float s0 = acc[0] * yls[wv * 16 + grp * 4 + 0][er];
    float s1 = acc[1] * yls[wv * 16 + grp * 4 + 1][er];
    float s2 = acc[2] * yls[wv * 16 + grp * 4 + 2][er];
    float s3 = acc[3] * yls[wv * 16 + grp * 4 + 3][er];
    #pragma unroll
    for (int m = 1; m < 16; m <<= 1) {
      s0 += __shfl_xor(s0, m);
      s1 += __shfl_xor(s1, m);
      s2 += __shfl_xor(s2, m);
      s3 += __shfl_xor(s3, m);
    }
    if (er < 4) {
      const float sv = er == 0 ? s0 : er == 1 ? s1 : er == 2 ? s2 : s3;
      out[(size_t)(b0 + wv * 16 + grp * 4 + er) * AA + (a0 + half)] = sv;
    }
  }
}

// ---------------------------------------------------------------------------
extern "C" void kernel_launch(void* const* d_in, const int* in_sizes, int n_in,
                              void* d_out, int out_size, void* d_ws, size_t ws_size,
                              hipStream_t stream) {
  const float* x  = (const float*)d_in[0];
  const float* y  = (const float*)d_in[1];
  const float* w1 = (const float*)d_in[2];
  const float* w2 = (const float*)d_in[3];
  const float* w3 = (const float*)d_in[4];
  const float* c1 = (const float*)d_in[5];
  const float* c2 = (const float*)d_in[6];
  const float* c3 = (const float*)d_in[7];
  const int* i1 = (const int*)d_in[8];
  const int* l1 = (const int*)d_in[9];
  const int* k1 = (const int*)d_in[10];
  const int* q1 = (const int*)d_in[11];
  const int* i2 = (const int*)d_in[12];
  const int* j2 = (const int*)d_in[13];
  const int* l2 = (const int*)d_in[14];
  const int* m2 = (const int*)d_in[15];
  const int* k2 = (const int*)d_in[16];
  const int* q2 = (const int*)d_in[17];
  const int* i3 = (const int*)d_in[18];
  const int* j3 = (const int*)d_in[19];
  const int* f3 = (const int*)d_in[20];
  const int* l3 = (const int*)d_in[21];
  const int* m3 = (const int*)d_in[22];
  const int* g3 = (const int*)d_in[23];
  const int* k3 = (const int*)d_in[24];
  const int* q3 = (const int*)d_in[25];

  unsigned* idxs = (unsigned*)d_ws;                    // 416*4 B
  short*    cwb  = (short*)((char*)d_ws + 4096);       // 64*13*64*8*2 B = 832 KB

  build_idx_kernel<<<1, 448, 0, stream>>>(i1, l1, i2, j2, l2, m2,
                                          i3, j3, f3, l3, m3, g3, idxs);
  build_cwb_kernel<<<AA * NKS, 64, 0, stream>>>(w1, w2, w3, c1, c2, c3,
                                                k1, q1, k2, q2, k3, q3, cwb);
  contract_kernel<<<(AA / 2) * (BB / BCH), 256, 0, stream>>>(
      x, y, idxs, (const bf16x8*)cwb, (float*)d_out);
}

// Round 6
// 47.072 us; speedup vs baseline: 3.7993x; 1.0706x over previous
//
#include <hip/hip_runtime.h>
#include <hip/hip_bf16.h>

typedef short  bf16x8 __attribute__((ext_vector_type(8)));
typedef float  f32x4  __attribute__((ext_vector_type(4)));

constexpr int BB  = 4096;
constexpr int AA  = 64;
constexpr int ED  = 10;
constexpr int P1N = 32, P2N = 128, P3N = 256;
constexpr int PT  = 416;          // = 13 * 32
constexpr int NKS = 13;           // K-steps of 32
constexpr int KSPL = 7;           // k-half split: [0,7) / [7,13)
constexpr int BCH = 32;           // b rows per block
constexpr int NCH = 4;            // a-channels per block

__device__ inline short f2bf(float f) {
  __hip_bfloat16 h = __float2bfloat16(f);
  short s;
  __builtin_memcpy(&s, &h, 2);
  return s;
}

// ---------------------------------------------------------------------------
// idxs[p] = sa | sb<<10 | sc<<20   (slot 0..64; 64 = constant-1 slot)
// ---------------------------------------------------------------------------
__global__ void build_idx_kernel(
    const int* __restrict__ i1, const int* __restrict__ l1,
    const int* __restrict__ i2, const int* __restrict__ j2,
    const int* __restrict__ l2, const int* __restrict__ m2,
    const int* __restrict__ i3, const int* __restrict__ j3,
    const int* __restrict__ f3, const int* __restrict__ l3,
    const int* __restrict__ m3, const int* __restrict__ g3,
    unsigned* __restrict__ idxs) {
  const int p = threadIdx.x;
  if (p >= PT) return;
  unsigned sa, sb = 64, sc = 64;
  if (p < P1N) {
    sa = i1[p] * 4 + l1[p];
  } else if (p < P1N + P2N) {
    int pp = p - P1N;
    sa = i2[pp] * 4 + l2[pp];
    sb = j2[pp] * 4 + m2[pp];
  } else {
    int pp = p - P1N - P2N;
    sa = i3[pp] * 4 + l3[pp];
    sb = j3[pp] * 4 + m3[pp];
    sc = f3[pp] * 4 + g3[pp];
  }
  idxs[p] = sa | (sb << 10) | (sc << 20);
}

// ---------------------------------------------------------------------------
// B-frag table: cwb[a][ks][lane][j] = bf16( coeff[p] * w[e,k[p],q[p],a] )
// p = ks*32 + (lane>>4)*8 + j, e = lane&15 (0 for e>=10).
// ---------------------------------------------------------------------------
__global__ void build_cwb_kernel(
    const float* __restrict__ w1, const float* __restrict__ w2, const float* __restrict__ w3,
    const float* __restrict__ c1, const float* __restrict__ c2, const float* __restrict__ c3,
    const int* __restrict__ k1, const int* __restrict__ q1,
    const int* __restrict__ k2, const int* __restrict__ q2,
    const int* __restrict__ k3, const int* __restrict__ q3,
    short* __restrict__ cwb) {
  const int a  = blockIdx.x & 63;
  const int ks = blockIdx.x >> 6;   // 0..12
  const int l  = threadIdx.x;       // 0..63
  const int grp = l >> 4, e = l & 15;
  short* dst = cwb + (((size_t)a * NKS + ks) * 64 + l) * 8;
  #pragma unroll
  for (int j = 0; j < 8; ++j) {
    const int p = ks * 32 + grp * 8 + j;
    float v = 0.f;
    if (e < ED) {
      const float* w; float coeff; int k, q, K, Q;
      if (p < P1N)            { w = w1; coeff = c1[p]; k = k1[p]; q = q1[p]; K = 4;  Q = 2; }
      else if (p < P1N + P2N) { int pp = p - P1N;       w = w2; coeff = c2[pp]; k = k2[pp]; q = q2[pp]; K = 16; Q = 4; }
      else                    { int pp = p - P1N - P2N; w = w3; coeff = c3[pp]; k = k3[pp]; q = q3[pp]; K = 32; Q = 6; }
      v = coeff * w[(((size_t)e * K + k) * Q + q) * AA + a];
    }
    dst[j] = f2bf(v);
  }
}

// ---------------------------------------------------------------------------
// K-step: one ds_read_b128 gather serves 4 a-channels.
// ---------------------------------------------------------------------------
template <int NF>
__device__ __forceinline__ void kstep4(const f32x4* __restrict__ row,
                                       const uint4* __restrict__ ip, int ks,
                                       const bf16x8* __restrict__ cw0,
                                       const bf16x8* __restrict__ cw1,
                                       const bf16x8* __restrict__ cw2,
                                       const bf16x8* __restrict__ cw3,
                                       f32x4& ac0, f32x4& ac1, f32x4& ac2, f32x4& ac3) {
  const uint4 iA = ip[ks * 8 + 0];
  const uint4 iB = ip[ks * 8 + 1];
  const bf16x8 b0 = cw0[ks * 64];
  const bf16x8 b1 = cw1[ks * 64];
  const bf16x8 b2 = cw2[ks * 64];
  const bf16x8 b3 = cw3[ks * 64];
  const unsigned pks[8] = {iA.x, iA.y, iA.z, iA.w, iB.x, iB.y, iB.z, iB.w};
  bf16x8 a0, a1, a2, a3;
  #pragma unroll
  for (int j = 0; j < 8; ++j) {
    const unsigned pk = pks[j];
    f32x4 v = row[pk & 1023u];
    if (NF >= 2) v = v * row[(pk >> 10) & 1023u];
    if (NF >= 3) v = v * row[pk >> 20];
    a0[j] = f2bf(v.x); a1[j] = f2bf(v.y); a2[j] = f2bf(v.z); a3[j] = f2bf(v.w);
  }
  ac0 = __builtin_amdgcn_mfma_f32_16x16x32_bf16(a0, b0, ac0, 0, 0, 0);
  ac1 = __builtin_amdgcn_mfma_f32_16x16x32_bf16(a1, b1, ac1, 0, 0, 0);
  ac2 = __builtin_amdgcn_mfma_f32_16x16x32_bf16(a2, b2, ac2, 0, 0, 0);
  ac3 = __builtin_amdgcn_mfma_f32_16x16x32_bf16(a3, b3, ac3, 0, 0, 0);
}

// ---------------------------------------------------------------------------
// Main: block = a-quad (a0..a0+3) x 32 b's. 4 waves = 2 M-tiles x 2 k-halves.
// wave w: mt = w&1 (rows mt*16..+15), kh = w>>1 (ks [0,7) or [7,13)).
// k-half partials combined through reused xls space (stride-17 scratch).
// ---------------------------------------------------------------------------
__global__ __launch_bounds__(256, 4)
void contract_kernel(const float* __restrict__ x, const float* __restrict__ y,
                     const unsigned* __restrict__ idxs,
                     const bf16x8* __restrict__ cwb,
                     float* __restrict__ out) {
  __shared__ f32x4 xls[BCH][65];   // slot 64 = {1,1,1,1}; 33.3 KB
  __shared__ float yls[BCH][17];   // e padded to 16 with zeros

  const int t  = threadIdx.x;
  const int a0 = (blockIdx.x & 15) * NCH;
  const int b0 = (blockIdx.x >> 4) * BCH;

  // Stage x: lane = slot; 4 coalesced dword loads -> one conflict-free b128 write.
  for (int u = t; u < BCH * 64; u += 256) {
    const int b = u >> 6, s = u & 63;
    const float* xb = x + (size_t)(b0 + b) * 4096 + a0 * 64 + s;
    f32x4 v;
    v.x = xb[0]; v.y = xb[64]; v.z = xb[128]; v.w = xb[192];
    xls[b][s] = v;
  }
  if (t < BCH) {
    xls[t][64] = f32x4{1.f, 1.f, 1.f, 1.f};
    const float* yb = y + (size_t)(b0 + t) * ED;
    #pragma unroll
    for (int e = 0; e < ED; ++e) yls[t][e] = yb[e];
    #pragma unroll
    for (int e = ED; e < 16; ++e) yls[t][e] = 0.f;
  }
  __syncthreads();

  const int wv = t >> 6, l = t & 63, grp = l >> 4, er = l & 15;
  const int mt = wv & 1;            // M-tile (16 rows)
  const int kh = wv >> 1;           // k-half
  const f32x4* __restrict__ row = &xls[mt * 16 + er][0];   // A-row = lane&15
  const bf16x8* __restrict__ cw0 = cwb + ((size_t)(a0 + 0) * NKS) * 64 + l;
  const bf16x8* __restrict__ cw1 = cwb + ((size_t)(a0 + 1) * NKS) * 64 + l;
  const bf16x8* __restrict__ cw2 = cwb + ((size_t)(a0 + 2) * NKS) * 64 + l;
  const bf16x8* __restrict__ cw3 = cwb + ((size_t)(a0 + 3) * NKS) * 64 + l;
  const uint4*  __restrict__ ip  = (const uint4*)idxs + grp * 2;

  f32x4 ac0 = {0.f, 0.f, 0.f, 0.f};
  f32x4 ac1 = {0.f, 0.f, 0.f, 0.f};
  f32x4 ac2 = {0.f, 0.f, 0.f, 0.f};
  f32x4 ac3 = {0.f, 0.f, 0.f, 0.f};

  if (kh == 0) {
    kstep4<1>(row, ip, 0, cw0, cw1, cw2, cw3, ac0, ac1, ac2, ac3);   // path1
    #pragma unroll 2
    for (int ks = 1; ks < 5; ++ks)                                    // path2
      kstep4<2>(row, ip, ks, cw0, cw1, cw2, cw3, ac0, ac1, ac2, ac3);
    #pragma unroll 2
    for (int ks = 5; ks < KSPL; ++ks)                                 // path3
      kstep4<3>(row, ip, ks, cw0, cw1, cw2, cw3, ac0, ac1, ac2, ac3);
  } else {
    #pragma unroll 2
    for (int ks = KSPL; ks < NKS; ++ks)                               // path3
      kstep4<3>(row, ip, ks, cw0, cw1, cw2, cw3, ac0, ac1, ac2, ac3);
  }

  // Combine k-halves through reused xls space (stride 17: bijective banks).
  __syncthreads();
  float* scr = (float*)&xls[0][0];    // 2*64*17 floats = 8.7 KB << 33.3 KB
  const int sbase = (mt * 64 + l) * 17;
  if (kh == 1) {
    #pragma unroll
    for (int v = 0; v < 4; ++v) {
      scr[sbase + v + 0]  = ac0[v];
      scr[sbase + v + 4]  = ac1[v];
      scr[sbase + v + 8]  = ac2[v];
      scr[sbase + v + 12] = ac3[v];
    }
  }
  __syncthreads();
  if (kh == 0) {
    #pragma unroll
    for (int v = 0; v < 4; ++v) {
      ac0[v] += scr[sbase + v + 0];
      ac1[v] += scr[sbase + v + 4];
      ac2[v] += scr[sbase + v + 8];
      ac3[v] += scr[sbase + v + 12];
    }
    // Epilogue: D[row = mt*16+grp*4+v][col = er], y-weight, reduce over e.
    #pragma unroll
    for (int c = 0; c < NCH; ++c) {
      const f32x4 acc = c == 0 ? ac0 : c == 1 ? ac1 : c == 2 ? ac2 : ac3;
      float s0 = acc[0] * yls[mt * 16 + grp * 4 + 0][er];
      float s1 = acc[1] * yls[mt * 16 + grp * 4 + 1][er];
      float s2 = acc[2] * yls[mt * 16 + grp * 4 + 2][er];
      float s3 = acc[3] * yls[mt * 16 + grp * 4 + 3][er];
      #pragma unroll
      for (int m = 1; m < 16; m <<= 1) {
        s0 += __shfl_xor(s0, m);
        s1 += __shfl_xor(s1, m);
        s2 += __shfl_xor(s2, m);
        s3 += __shfl_xor(s3, m);
      }
      if (er < 4) {
        const float sv = er == 0 ? s0 : er == 1 ? s1 : er == 2 ? s2 : s3;
        out[(size_t)(b0 + mt * 16 + grp * 4 + er) * AA + (a0 + c)] = sv;
      }
    }
  }
}

// ---------------------------------------------------------------------------
extern "C" void kernel_launch(void* const* d_in, const int* in_sizes, int n_in,
                              void* d_out, int out_size, void* d_ws, size_t ws_size,
                              hipStream_t stream) {
  const float* x  = (const float*)d_in[0];
  const float* y  = (const float*)d_in[1];
  const float* w1 = (const float*)d_in[2];
  const float* w2 = (const float*)d_in[3];
  const float* w3 = (const float*)d_in[4];
  const float* c1 = (const float*)d_in[5];
  const float* c2 = (const float*)d_in[6];
  const float* c3 = (const float*)d_in[7];
  const int* i1 = (const int*)d_in[8];
  const int* l1 = (const int*)d_in[9];
  const int* k1 = (const int*)d_in[10];
  const int* q1 = (const int*)d_in[11];
  const int* i2 = (const int*)d_in[12];
  const int* j2 = (const int*)d_in[13];
  const int* l2 = (const int*)d_in[14];
  const int* m2 = (const int*)d_in[15];
  const int* k2 = (const int*)d_in[16];
  const int* q2 = (const int*)d_in[17];
  const int* i3 = (const int*)d_in[18];
  const int* j3 = (const int*)d_in[19];
  const int* f3 = (const int*)d_in[20];
  const int* l3 = (const int*)d_in[21];
  const int* m3 = (const int*)d_in[22];
  const int* g3 = (const int*)d_in[23];
  const int* k3 = (const int*)d_in[24];
  const int* q3 = (const int*)d_in[25];

  unsigned* idxs = (unsigned*)d_ws;                    // 416*4 B
  short*    cwb  = (short*)((char*)d_ws + 4096);       // 832 KB

  build_idx_kernel<<<1, 448, 0, stream>>>(i1, l1, i2, j2, l2, m2,
                                          i3, j3, f3, l3, m3, g3, idxs);
  build_cwb_kernel<<<AA * NKS, 64, 0, stream>>>(w1, w2, w3, c1, c2, c3,
                                                k1, q1, k2, q2, k3, q3, cwb);
  contract_kernel<<<(AA / NCH) * (BB / BCH), 256, 0, stream>>>(
      x, y, idxs, (const bf16x8*)cwb, (float*)d_out);
}

// Round 7
// 46.248 us; speedup vs baseline: 3.8670x; 1.0178x over previous
//
#include <hip/hip_runtime.h>
#include <hip/hip_bf16.h>

typedef short  bf16x8 __attribute__((ext_vector_type(8)));
typedef float  f32x4  __attribute__((ext_vector_type(4)));
typedef float  f32x2  __attribute__((ext_vector_type(2)));

constexpr int BB  = 4096;
constexpr int AA  = 64;
constexpr int ED  = 10;
constexpr int P1N = 32, P2N = 128, P3N = 256;
constexpr int PT  = 416;          // = 13 * 32
constexpr int NKS = 13;           // K-steps of 32
constexpr int KSPL = 7;           // k-half split: [0,7) / [7,13)
constexpr int BCH = 32;           // b rows per block
constexpr int NCH = 2;            // a-channels per block

__device__ inline short f2bf(float f) {
  __hip_bfloat16 h = __float2bfloat16(f);
  short s;
  __builtin_memcpy(&s, &h, 2);
  return s;
}

// ---------------------------------------------------------------------------
// idxs[p] = sa | sb<<10 | sc<<20   (slot 0..64; 64 = constant-1 slot)
// ---------------------------------------------------------------------------
__global__ void build_idx_kernel(
    const int* __restrict__ i1, const int* __restrict__ l1,
    const int* __restrict__ i2, const int* __restrict__ j2,
    const int* __restrict__ l2, const int* __restrict__ m2,
    const int* __restrict__ i3, const int* __restrict__ j3,
    const int* __restrict__ f3, const int* __restrict__ l3,
    const int* __restrict__ m3, const int* __restrict__ g3,
    unsigned* __restrict__ idxs) {
  const int p = threadIdx.x;
  if (p >= PT) return;
  unsigned sa, sb = 64, sc = 64;
  if (p < P1N) {
    sa = i1[p] * 4 + l1[p];
  } else if (p < P1N + P2N) {
    int pp = p - P1N;
    sa = i2[pp] * 4 + l2[pp];
    sb = j2[pp] * 4 + m2[pp];
  } else {
    int pp = p - P1N - P2N;
    sa = i3[pp] * 4 + l3[pp];
    sb = j3[pp] * 4 + m3[pp];
    sc = f3[pp] * 4 + g3[pp];
  }
  idxs[p] = sa | (sb << 10) | (sc << 20);
}

// ---------------------------------------------------------------------------
// B-frag table: cwb[a][ks][lane][j] = bf16( coeff[p] * w[e,k[p],q[p],a] )
// p = ks*32 + (lane>>4)*8 + j, e = lane&15 (0 for e>=10).
// ---------------------------------------------------------------------------
__global__ void build_cwb_kernel(
    const float* __restrict__ w1, const float* __restrict__ w2, const float* __restrict__ w3,
    const float* __restrict__ c1, const float* __restrict__ c2, const float* __restrict__ c3,
    const int* __restrict__ k1, const int* __restrict__ q1,
    const int* __restrict__ k2, const int* __restrict__ q2,
    const int* __restrict__ k3, const int* __restrict__ q3,
    short* __restrict__ cwb) {
  const int a  = blockIdx.x & 63;
  const int ks = blockIdx.x >> 6;   // 0..12
  const int l  = threadIdx.x;       // 0..63
  const int grp = l >> 4, e = l & 15;
  short* dst = cwb + (((size_t)a * NKS + ks) * 64 + l) * 8;
  #pragma unroll
  for (int j = 0; j < 8; ++j) {
    const int p = ks * 32 + grp * 8 + j;
    float v = 0.f;
    if (e < ED) {
      const float* w; float coeff; int k, q, K, Q;
      if (p < P1N)            { w = w1; coeff = c1[p]; k = k1[p]; q = q1[p]; K = 4;  Q = 2; }
      else if (p < P1N + P2N) { int pp = p - P1N;       w = w2; coeff = c2[pp]; k = k2[pp]; q = q2[pp]; K = 16; Q = 4; }
      else                    { int pp = p - P1N - P2N; w = w3; coeff = c3[pp]; k = k3[pp]; q = q3[pp]; K = 32; Q = 6; }
      v = coeff * w[(((size_t)e * K + k) * Q + q) * AA + a];
    }
    dst[j] = f2bf(v);
  }
}

// ---------------------------------------------------------------------------
// K-step: one ds_read_b64 gather serves 2 a-channels.
// ---------------------------------------------------------------------------
template <int NF>
__device__ __forceinline__ void kstep2(const f32x2* __restrict__ row,
                                       const uint4* __restrict__ ip, int ks,
                                       const bf16x8* __restrict__ cw0,
                                       const bf16x8* __restrict__ cw1,
                                       f32x4& ac0, f32x4& ac1) {
  const uint4 iA = ip[ks * 8 + 0];
  const uint4 iB = ip[ks * 8 + 1];
  const bf16x8 b0 = cw0[ks * 64];
  const bf16x8 b1 = cw1[ks * 64];
  const unsigned pks[8] = {iA.x, iA.y, iA.z, iA.w, iB.x, iB.y, iB.z, iB.w};
  bf16x8 a0, a1;
  #pragma unroll
  for (int j = 0; j < 8; ++j) {
    const unsigned pk = pks[j];
    f32x2 v = row[pk & 1023u];
    if (NF >= 2) v = v * row[(pk >> 10) & 1023u];
    if (NF >= 3) v = v * row[pk >> 20];
    a0[j] = f2bf(v.x); a1[j] = f2bf(v.y);
  }
  ac0 = __builtin_amdgcn_mfma_f32_16x16x32_bf16(a0, b0, ac0, 0, 0, 0);
  ac1 = __builtin_amdgcn_mfma_f32_16x16x32_bf16(a1, b1, ac1, 0, 0, 0);
}

// ---------------------------------------------------------------------------
// Main: block = a-pair x 32 b's, 18.8 KB LDS -> 8 blocks/CU = 32 waves/CU.
// 4 waves = 2 M-tiles x 2 k-halves; k-half partials combined via LDS scratch.
// ---------------------------------------------------------------------------
__global__ __launch_bounds__(256, 8)
void contract_kernel(const float* __restrict__ x, const float* __restrict__ y,
                     const unsigned* __restrict__ idxs,
                     const bf16x8* __restrict__ cwb,
                     float* __restrict__ out) {
  __shared__ f32x2 xls[BCH][65];   // slot 64 = {1,1}; 16.6 KB
  __shared__ float yls[BCH][17];   // e padded to 16 with zeros

  const int t  = threadIdx.x;
  const int a0 = (blockIdx.x & 31) * NCH;
  const int b0 = (blockIdx.x >> 5) * BCH;

  // Stage x: lane = slot; 2 coalesced dword loads -> one ds_write_b64.
  for (int u = t; u < BCH * 64; u += 256) {
    const int b = u >> 6, s = u & 63;
    const float* xb = x + (size_t)(b0 + b) * 4096 + a0 * 64 + s;
    f32x2 v;
    v.x = xb[0]; v.y = xb[64];
    xls[b][s] = v;
  }
  if (t < BCH) {
    xls[t][64] = f32x2{1.f, 1.f};
    const float* yb = y + (size_t)(b0 + t) * ED;
    #pragma unroll
    for (int e = 0; e < ED; ++e) yls[t][e] = yb[e];
    #pragma unroll
    for (int e = ED; e < 16; ++e) yls[t][e] = 0.f;
  }
  __syncthreads();

  const int wv = t >> 6, l = t & 63, grp = l >> 4, er = l & 15;
  const int mt = wv & 1;            // M-tile (16 rows)
  const int kh = wv >> 1;           // k-half
  const f32x2* __restrict__ row = &xls[mt * 16 + er][0];   // A-row = lane&15
  const bf16x8* __restrict__ cw0 = cwb + ((size_t)(a0 + 0) * NKS) * 64 + l;
  const bf16x8* __restrict__ cw1 = cwb + ((size_t)(a0 + 1) * NKS) * 64 + l;
  const uint4*  __restrict__ ip  = (const uint4*)idxs + grp * 2;

  f32x4 ac0 = {0.f, 0.f, 0.f, 0.f};
  f32x4 ac1 = {0.f, 0.f, 0.f, 0.f};

  if (kh == 0) {
    kstep2<1>(row, ip, 0, cw0, cw1, ac0, ac1);            // path1: ks 0
    #pragma unroll 2
    for (int ks = 1; ks < 5; ++ks)                        // path2: ks 1..4
      kstep2<2>(row, ip, ks, cw0, cw1, ac0, ac1);
    #pragma unroll 2
    for (int ks = 5; ks < KSPL; ++ks)                     // path3: ks 5..6
      kstep2<3>(row, ip, ks, cw0, cw1, ac0, ac1);
  } else {
    #pragma unroll 2
    for (int ks = KSPL; ks < NKS; ++ks)                   // path3: ks 7..12
      kstep2<3>(row, ip, ks, cw0, cw1, ac0, ac1);
  }

  // Combine k-halves through reused xls space (stride 9: gcd(9,32)=1 banks).
  __syncthreads();
  float* scr = (float*)&xls[0][0];    // 2*64*9 floats = 4.6 KB << 16.6 KB
  const int sbase = (mt * 64 + l) * 9;
  if (kh == 1) {
    #pragma unroll
    for (int v = 0; v < 4; ++v) {
      scr[sbase + v + 0] = ac0[v];
      scr[sbase + v + 4] = ac1[v];
    }
  }
  __syncthreads();
  if (kh == 0) {
    #pragma unroll
    for (int v = 0; v < 4; ++v) {
      ac0[v] += scr[sbase + v + 0];
      ac1[v] += scr[sbase + v + 4];
    }
    // Epilogue: D[row = mt*16+grp*4+v][col = er], y-weight, reduce over e.
    #pragma unroll
    for (int c = 0; c < NCH; ++c) {
      const f32x4 acc = c == 0 ? ac0 : ac1;
      float s0 = acc[0] * yls[mt * 16 + grp * 4 + 0][er];
      float s1 = acc[1] * yls[mt * 16 + grp * 4 + 1][er];
      float s2 = acc[2] * yls[mt * 16 + grp * 4 + 2][er];
      float s3 = acc[3] * yls[mt * 16 + grp * 4 + 3][er];
      #pragma unroll
      for (int m = 1; m < 16; m <<= 1) {
        s0 += __shfl_xor(s0, m);
        s1 += __shfl_xor(s1, m);
        s2 += __shfl_xor(s2, m);
        s3 += __shfl_xor(s3, m);
      }
      if (er < 4) {
        const float sv = er == 0 ? s0 : er == 1 ? s1 : er == 2 ? s2 : s3;
        out[(size_t)(b0 + mt * 16 + grp * 4 + er) * AA + (a0 + c)] = sv;
      }
    }
  }
}

// ---------------------------------------------------------------------------
extern "C" void kernel_launch(void* const* d_in, const int* in_sizes, int n_in,
                              void* d_out, int out_size, void* d_ws, size_t ws_size,
                              hipStream_t stream) {
  const float* x  = (const float*)d_in[0];
  const float* y  = (const float*)d_in[1];
  const float* w1 = (const float*)d_in[2];
  const float* w2 = (const float*)d_in[3];
  const float* w3 = (const float*)d_in[4];
  const float* c1 = (const float*)d_in[5];
  const float* c2 = (const float*)d_in[6];
  const float* c3 = (const float*)d_in[7];
  const int* i1 = (const int*)d_in[8];
  const int* l1 = (const int*)d_in[9];
  const int* k1 = (const int*)d_in[10];
  const int* q1 = (const int*)d_in[11];
  const int* i2 = (const int*)d_in[12];
  const int* j2 = (const int*)d_in[13];
  const int* l2 = (const int*)d_in[14];
  const int* m2 = (const int*)d_in[15];
  const int* k2 = (const int*)d_in[16];
  const int* q2 = (const int*)d_in[17];
  const int* i3 = (const int*)d_in[18];
  const int* j3 = (const int*)d_in[19];
  const int* f3 = (const int*)d_in[20];
  const int* l3 = (const int*)d_in[21];
  const int* m3 = (const int*)d_in[22];
  const int* g3 = (const int*)d_in[23];
  const int* k3 = (const int*)d_in[24];
  const int* q3 = (const int*)d_in[25];

  unsigned* idxs = (unsigned*)d_ws;                    // 416*4 B
  short*    cwb  = (short*)((char*)d_ws + 4096);       // 832 KB

  build_idx_kernel<<<1, 448, 0, stream>>>(i1, l1, i2, j2, l2, m2,
                                          i3, j3, f3, l3, m3, g3, idxs);
  build_cwb_kernel<<<AA * NKS, 64, 0, stream>>>(w1, w2, w3, c1, c2, c3,
                                                k1, q1, k2, q2, k3, q3, cwb);
  contract_kernel<<<(AA / NCH) * (BB / BCH), 256, 0, stream>>>(
      x, y, idxs, (const bf16x8*)cwb, (float*)d_out);
}